// Round 2
// baseline (811.495 us; speedup 1.0000x reference)
//
#include <hip/hip_runtime.h>
#include <math.h>

// (B, L, D_MODEL, H) = (8, 512, 512, 8), dh = 64
typedef __attribute__((ext_vector_type(8))) short bf16x8;
typedef __attribute__((ext_vector_type(4))) float f32x4;

// ---------------------------------------------------------------------------
// bf16 split helpers: f = hi + lo + O(2^-17 * |f|)
// ---------------------------------------------------------------------------
__device__ __forceinline__ unsigned short bf16_rne(float f) {
    unsigned int u = __float_as_uint(f);
    unsigned int r = (u + 0x7fffu + ((u >> 16) & 1u)) >> 16;
    return (unsigned short)r;
}
__device__ __forceinline__ float bf16_to_f32(unsigned short h) {
    return __uint_as_float(((unsigned int)h) << 16);
}
__device__ __forceinline__ void split_bf16(float f, unsigned short& h, unsigned short& l) {
    h = bf16_rne(f);
    l = bf16_rne(f - bf16_to_f32(h));
}
// async global->LDS, 16B per lane; lds dest = uniform base + lane*16
__device__ __forceinline__ void gll16(const void* g, void* l) {
    __builtin_amdgcn_global_load_lds((const __attribute__((address_space(1))) void*)g,
                                     (__attribute__((address_space(3))) void*)l, 16, 0, 0);
}

// ---------------------------------------------------------------------------
// Kernel 1 (fused prep):
//  blocks [0, 65536): biasQK[q][k] = sum_d rel[q][k][d]   (512 MB HBM read)
//  blocks [65536, 68608): f32 -> bf16 hi/lo conversion of x, Wq, Wk, Wv, Wo
//  blocks [68608, 68672): RoPE sin/cos tables  table[pos*32 + p]
// ---------------------------------------------------------------------------
__global__ __launch_bounds__(256) void prep_kernel(
    const float* __restrict__ rel, const float* __restrict__ x,
    const float* __restrict__ Wq, const float* __restrict__ Wk,
    const float* __restrict__ Wv, const float* __restrict__ Wo,
    float* __restrict__ biasQK, float* __restrict__ sin_t, float* __restrict__ cos_t,
    unsigned short* __restrict__ xh, unsigned short* __restrict__ xl,
    unsigned short* __restrict__ Wqh, unsigned short* __restrict__ Wql,
    unsigned short* __restrict__ Wkh, unsigned short* __restrict__ Wkl,
    unsigned short* __restrict__ Wvh, unsigned short* __restrict__ Wvl,
    unsigned short* __restrict__ Woh, unsigned short* __restrict__ Wol)
{
    const int bid = blockIdx.x, tid = threadIdx.x;
    if (bid < 65536) {
        // one wave per reduction row (262144 rows of 512 f32)
        int gw = bid * 4 + (tid >> 6);
        int lane = tid & 63;
        const float4* row = (const float4*)(rel + (size_t)gw * 512);
        float4 a = row[lane];
        float4 b = row[lane + 64];
        float s = (a.x + a.y) + (a.z + a.w) + (b.x + b.y) + (b.z + b.w);
        #pragma unroll
        for (int off = 32; off > 0; off >>= 1) s += __shfl_down(s, off);
        if (lane == 0) biasQK[gw] = s;
    } else if (bid < 65536 + 3072) {
        int cb = bid - 65536;
        const float* src; unsigned short* dh; unsigned short* dl; int base;
        if (cb < 2048) { src = x; dh = xh; dl = xl; base = cb * 1024; }
        else {
            int s2 = (cb - 2048) >> 8;
            base = ((cb - 2048) & 255) * 1024;
            if (s2 == 0)      { src = Wq; dh = Wqh; dl = Wql; }
            else if (s2 == 1) { src = Wk; dh = Wkh; dl = Wkl; }
            else if (s2 == 2) { src = Wv; dh = Wvh; dl = Wvl; }
            else              { src = Wo; dh = Woh; dl = Wol; }
        }
        int e = base + tid * 4;
        float4 v = *(const float4*)(src + e);
        ushort4 h4, l4;
        split_bf16(v.x, h4.x, l4.x); split_bf16(v.y, h4.y, l4.y);
        split_bf16(v.z, h4.z, l4.z); split_bf16(v.w, h4.w, l4.w);
        *(ushort4*)(dh + e) = h4;
        *(ushort4*)(dl + e) = l4;
    } else {
        int t = (bid - 68608) * 256 + tid;   // < 16384
        int pos = t >> 5, p = t & 31;
        // ln(10000)/32 = 0.2878231366242557
        float freq = expf(-0.2878231366242557f * (float)p);
        float ang = (float)pos * freq;
        float s, c;
        sincosf(ang, &s, &c);
        sin_t[t] = s; cos_t[t] = c;
    }
}

// ---------------------------------------------------------------------------
// bf16x3 MFMA GEMM core: D(128x128) = A(128x512) * B(128x512)^T in ~f32
// precision.  A,B given as bf16 hi/lo pairs, row-major, ld = 512.
// 256 threads = 4 waves (2x2); wave tile 64x64 = 4x4 fragments of 16x16x32.
// Fragment layout (m89/m92-verified): a/b lane: row = lane&15, k-octet =
// (lane>>4)*8; D: col = lane&15, row = (lane>>4)*4 + reg.
// LDS: 4 linear tiles [128][32] bf16 (8 KB each), staged via global_load_lds.
// ---------------------------------------------------------------------------
__device__ __forceinline__ void mfma_core_128(
    const unsigned short* __restrict__ Ah, const unsigned short* __restrict__ Al, int aRow0,
    const unsigned short* __restrict__ Bh, const unsigned short* __restrict__ Bl, int bRow0,
    unsigned short* sAh, unsigned short* sAl, unsigned short* sBh, unsigned short* sBl,
    f32x4 (&acc)[4][4], int wid, int lane, int wr, int wc)
{
    #pragma unroll
    for (int i = 0; i < 4; ++i)
        #pragma unroll
        for (int j = 0; j < 4; ++j)
            acc[i][j] = (f32x4){0.f, 0.f, 0.f, 0.f};

    const int srow = wid * 32 + (lane >> 2);   // staging row within tile
    const int scol = (lane & 3) * 8;           // staging col (bf16 elems)

    for (int k0 = 0; k0 < 512; k0 += 32) {
        // stage 4 tensors; wave w fills tile rows [w*32, w*32+32)
        #pragma unroll
        for (int hh = 0; hh < 2; ++hh) {
            int r = srow + hh * 16;
            size_t ga = (size_t)(aRow0 + r) * 512 + k0 + scol;
            size_t gb = (size_t)(bRow0 + r) * 512 + k0 + scol;
            int lofs = wid * 2048 + hh * 1024;
            gll16(Ah + ga, (char*)sAh + lofs);
            gll16(Al + ga, (char*)sAl + lofs);
            gll16(Bh + gb, (char*)sBh + lofs);
            gll16(Bl + gb, (char*)sBl + lofs);
        }
        __syncthreads();   // drains vmcnt, staging visible

        bf16x8 ah[4], al[4], bh[4], bl[4];
        const int ob = (lane >> 4) * 16;       // k-octet byte offset
        #pragma unroll
        for (int i = 0; i < 4; ++i) {
            int rowA = wr * 64 + i * 16 + (lane & 15);
            int rowB = wc * 64 + i * 16 + (lane & 15);
            ah[i] = *(const bf16x8*)((const char*)sAh + rowA * 64 + ob);
            al[i] = *(const bf16x8*)((const char*)sAl + rowA * 64 + ob);
            bh[i] = *(const bf16x8*)((const char*)sBh + rowB * 64 + ob);
            bl[i] = *(const bf16x8*)((const char*)sBl + rowB * 64 + ob);
        }
        #pragma unroll
        for (int i = 0; i < 4; ++i)
            #pragma unroll
            for (int j = 0; j < 4; ++j) {
                acc[i][j] = __builtin_amdgcn_mfma_f32_16x16x32_bf16(ah[i], bh[j], acc[i][j], 0, 0, 0);
                acc[i][j] = __builtin_amdgcn_mfma_f32_16x16x32_bf16(ah[i], bl[j], acc[i][j], 0, 0, 0);
                acc[i][j] = __builtin_amdgcn_mfma_f32_16x16x32_bf16(al[i], bh[j], acc[i][j], 0, 0, 0);
            }
        __syncthreads();   // all reads done before next stage overwrites
    }
}

// ---------------------------------------------------------------------------
// Kernel 2: QKV projections.  grid (128, 3); z = blockIdx.y in {Q, K, V}.
// Q/K: TRANSPOSED orientation  D[feature][token] = W * x^T  so RoPE pairs
// (2p, 2p+1) sit in adjacent regs (lane-local); stored as Qt/Kt [bh][d][l].
// V: normal orientation D[token][feature], stored Vw[bh][l][d].
// ---------------------------------------------------------------------------
__global__ __launch_bounds__(256) void qkv_mfma_kernel(
    const unsigned short* __restrict__ xh, const unsigned short* __restrict__ xl,
    const unsigned short* __restrict__ Wqh, const unsigned short* __restrict__ Wql,
    const unsigned short* __restrict__ Wkh, const unsigned short* __restrict__ Wkl,
    const unsigned short* __restrict__ Wvh, const unsigned short* __restrict__ Wvl,
    const float* __restrict__ bq, const float* __restrict__ bk, const float* __restrict__ bv,
    const float* __restrict__ sin_t, const float* __restrict__ cos_t,
    float* __restrict__ Qt, float* __restrict__ Kt, float* __restrict__ Vw)
{
    __shared__ unsigned short sAh[4096], sAl[4096], sBh[4096], sBl[4096];
    const int tid = threadIdx.x, lane = tid & 63, wid = tid >> 6;
    const int wr = wid >> 1, wc = wid & 1;
    const int z = blockIdx.y;
    const int fTile = blockIdx.x >> 5;   // 0..3   (feature tiles, 128 wide)
    const int tTile = blockIdx.x & 31;   // 0..31  (token tiles, 128 wide)

    f32x4 acc[4][4];
    if (z < 2) {
        const unsigned short* Wh = z ? Wkh : Wqh;
        const unsigned short* Wl = z ? Wkl : Wql;
        mfma_core_128(Wh, Wl, fTile * 128, xh, xl, tTile * 128,
                      sAh, sAl, sBh, sBl, acc, wid, lane, wr, wc);
        const float* bias = z ? bk : bq;
        float* outp = z ? Kt : Qt;
        const int h  = fTile * 2 + wr;           // wave = one head (64 rows)
        const int bb = (tTile * 128) >> 9;       // batch (tile within one batch)
        const int bh = bb * 8 + h;
        #pragma unroll
        for (int i = 0; i < 4; ++i) {
            int d0 = i * 16 + (lane >> 4) * 4;   // head-feature of reg 0 (mult of 4)
            int f0 = fTile * 128 + wr * 64 + d0;
            float b0 = bias[f0], b1 = bias[f0 + 1], b2 = bias[f0 + 2], b3 = bias[f0 + 3];
            int p0 = d0 >> 1;                    // rope pair for regs (0,1); regs (2,3) -> p0+1
            #pragma unroll
            for (int j = 0; j < 4; ++j) {
                int t  = tTile * 128 + wc * 64 + j * 16 + (lane & 15);
                int lq = t & 511;
                float s0 = sin_t[lq * 32 + p0],     c0 = cos_t[lq * 32 + p0];
                float s1 = sin_t[lq * 32 + p0 + 1], c1 = cos_t[lq * 32 + p0 + 1];
                float X0 = acc[i][j][0] + b0, X1 = acc[i][j][1] + b1;
                float X2 = acc[i][j][2] + b2, X3 = acc[i][j][3] + b3;
                size_t base = ((size_t)bh * 64) * 512 + (size_t)lq;
                outp[base + (size_t)(p0) * 512]          = X0 * c0 - X1 * s0;
                outp[base + (size_t)(32 + p0) * 512]     = X0 * s0 + X1 * c0;
                outp[base + (size_t)(p0 + 1) * 512]      = X2 * c1 - X3 * s1;
                outp[base + (size_t)(32 + p0 + 1) * 512] = X2 * s1 + X3 * c1;
            }
        }
    } else {
        mfma_core_128(xh, xl, tTile * 128, Wvh, Wvl, fTile * 128,
                      sAh, sAl, sBh, sBl, acc, wid, lane, wr, wc);
        #pragma unroll
        for (int i = 0; i < 4; ++i) {
            int tBase = tTile * 128 + wr * 64 + i * 16 + (lane >> 4) * 4;
            #pragma unroll
            for (int j = 0; j < 4; ++j) {
                int f = fTile * 128 + wc * 64 + j * 16 + (lane & 15);
                float bvf = bv[f];
                int h = f >> 6, d = f & 63;
                #pragma unroll
                for (int r = 0; r < 4; ++r) {
                    int t = tBase + r;
                    int bb = t >> 9, lq = t & 511;
                    Vw[((size_t)(bb * 8 + h) * 512 + lq) * 64 + d] = acc[i][j][r] + bvf;
                }
            }
        }
    }
}

// ---------------------------------------------------------------------------
// Kernel 3: flash attention (f32).  Block = (q-tile of 64, bh); 256 threads
// as 16(qg) x 16(tx), thread owns 4 q x 4 cols.  Q/K arrive pre-transposed
// [bh][d][l] -> direct coalesced staging into Qt/Kt [d][l] LDS.
// Epilogue writes ctx as bf16 hi/lo for the MFMA output projection.
// ---------------------------------------------------------------------------
__global__ __launch_bounds__(256) void attn_kernel(const float* __restrict__ Qg,
    const float* __restrict__ Kg, const float* __restrict__ Vg,
    const float* __restrict__ biasQK,
    unsigned short* __restrict__ ctxh, unsigned short* __restrict__ ctxl)
{
    __shared__ float Qt[64][64];   // [d][q]
    __shared__ float Kt[64][64];   // [d][k]
    __shared__ float Vs[64][64];   // [k][d]
    __shared__ float Ps[64][68];   // [q][k], padded

    const int bh = blockIdx.y, b = bh >> 3, h = bh & 7;
    const int q0 = blockIdx.x * 64;
    const int tid = threadIdx.x;
    const int tx = tid & 15, qg = tid >> 4;

    // stage Q tile: Qt[d][q] <- Qg[(bh*64+d)*512 + q0+q]  (coalesced float4)
    #pragma unroll
    for (int it = 0; it < 4; ++it) {
        int idx = it * 256 + tid;
        int d = idx >> 4, c4 = idx & 15;
        *(float4*)&Qt[d][c4 * 4] =
            *(const float4*)&Qg[((size_t)bh * 64 + d) * 512 + q0 + c4 * 4];
    }

    float o[4][4];
    float mr[4], lr[4];
    #pragma unroll
    for (int i = 0; i < 4; ++i) {
        mr[i] = -1e30f; lr[i] = 0.f;
        o[i][0] = o[i][1] = o[i][2] = o[i][3] = 0.f;
    }

    for (int kt = 0; kt < 8; ++kt) {
        const int k0 = kt * 64;
        __syncthreads();   // previous tile fully consumed
        #pragma unroll
        for (int it = 0; it < 4; ++it) {
            int idx = it * 256 + tid;
            int d = idx >> 4, c4 = idx & 15;
            *(float4*)&Kt[d][c4 * 4] =
                *(const float4*)&Kg[((size_t)bh * 64 + d) * 512 + k0 + c4 * 4];
        }
        {
            const float4* vsrc = (const float4*)(Vg + ((size_t)bh * 512 + k0) * 64);
            float4* vdst = (float4*)&Vs[0][0];
            #pragma unroll
            for (int c = 0; c < 4; ++c) vdst[c * 256 + tid] = vsrc[c * 256 + tid];
        }
        __syncthreads();

        // S = Q^T K (4x4 per thread, over d)
        float s[4][4];
        #pragma unroll
        for (int i = 0; i < 4; ++i) s[i][0] = s[i][1] = s[i][2] = s[i][3] = 0.f;
        #pragma unroll 8
        for (int d = 0; d < 64; ++d) {
            float4 a  = *(const float4*)&Qt[d][qg * 4];
            float4 kk = *(const float4*)&Kt[d][tx * 4];
            float av[4] = {a.x, a.y, a.z, a.w};
            float kv[4] = {kk.x, kk.y, kk.z, kk.w};
            #pragma unroll
            for (int i = 0; i < 4; ++i) {
                #pragma unroll
                for (int j = 0; j < 4; ++j)
                    s[i][j] = fmaf(av[i], kv[j], s[i][j]);
            }
        }

        // scale + bias + online softmax (row stats across 16 tx lanes)
        #pragma unroll
        for (int i = 0; i < 4; ++i) {
            const int q = qg * 4 + i;
            float4 b4 = *(const float4*)&biasQK[(size_t)(q0 + q) * 512 + k0 + tx * 4];
            float sv0 = fmaf(s[i][0], 0.125f, b4.x);
            float sv1 = fmaf(s[i][1], 0.125f, b4.y);
            float sv2 = fmaf(s[i][2], 0.125f, b4.z);
            float sv3 = fmaf(s[i][3], 0.125f, b4.w);
            float tm = fmaxf(fmaxf(sv0, sv1), fmaxf(sv2, sv3));
            #pragma unroll
            for (int off = 1; off < 16; off <<= 1) tm = fmaxf(tm, __shfl_xor(tm, off));
            float mnew = fmaxf(mr[i], tm);
            float resc = __expf(mr[i] - mnew);
            mr[i] = mnew;
            float p0 = __expf(sv0 - mnew), p1 = __expf(sv1 - mnew);
            float p2 = __expf(sv2 - mnew), p3 = __expf(sv3 - mnew);
            float rs = (p0 + p1) + (p2 + p3);
            #pragma unroll
            for (int off = 1; off < 16; off <<= 1) rs += __shfl_xor(rs, off);
            lr[i] = lr[i] * resc + rs;
            o[i][0] *= resc; o[i][1] *= resc; o[i][2] *= resc; o[i][3] *= resc;
            *(float4*)&Ps[q][tx * 4] = make_float4(p0, p1, p2, p3);
        }
        __syncthreads();

        // O += P * V
        #pragma unroll 8
        for (int k = 0; k < 64; ++k) {
            float4 vvv = *(const float4*)&Vs[k][tx * 4];
            float p0 = Ps[qg * 4 + 0][k];
            float p1 = Ps[qg * 4 + 1][k];
            float p2 = Ps[qg * 4 + 2][k];
            float p3 = Ps[qg * 4 + 3][k];
            o[0][0] = fmaf(p0, vvv.x, o[0][0]); o[0][1] = fmaf(p0, vvv.y, o[0][1]);
            o[0][2] = fmaf(p0, vvv.z, o[0][2]); o[0][3] = fmaf(p0, vvv.w, o[0][3]);
            o[1][0] = fmaf(p1, vvv.x, o[1][0]); o[1][1] = fmaf(p1, vvv.y, o[1][1]);
            o[1][2] = fmaf(p1, vvv.z, o[1][2]); o[1][3] = fmaf(p1, vvv.w, o[1][3]);
            o[2][0] = fmaf(p2, vvv.x, o[2][0]); o[2][1] = fmaf(p2, vvv.y, o[2][1]);
            o[2][2] = fmaf(p2, vvv.z, o[2][2]); o[2][3] = fmaf(p2, vvv.w, o[2][3]);
            o[3][0] = fmaf(p3, vvv.x, o[3][0]); o[3][1] = fmaf(p3, vvv.y, o[3][1]);
            o[3][2] = fmaf(p3, vvv.z, o[3][2]); o[3][3] = fmaf(p3, vvv.w, o[3][3]);
        }
    }

    // normalize + split to bf16 hi/lo ctx[b][l][h*64+d]
    #pragma unroll
    for (int i = 0; i < 4; ++i) {
        float inv = 1.0f / lr[i];
        int q = q0 + qg * 4 + i;
        ushort4 h4, l4;
        float v0 = o[i][0] * inv, v1 = o[i][1] * inv, v2 = o[i][2] * inv, v3 = o[i][3] * inv;
        split_bf16(v0, h4.x, l4.x); split_bf16(v1, h4.y, l4.y);
        split_bf16(v2, h4.z, l4.z); split_bf16(v3, h4.w, l4.w);
        size_t off = ((size_t)(b * 512 + q)) * 512 + h * 64 + tx * 4;
        *(ushort4*)(ctxh + off) = h4;
        *(ushort4*)(ctxl + off) = l4;
    }
}

// ---------------------------------------------------------------------------
// Kernel 4: output projection  out = ctx @ Wo^T + bo  (bf16x3 MFMA, normal
// orientation: rows = tokens, cols = features)
// ---------------------------------------------------------------------------
__global__ __launch_bounds__(256) void out_mfma_kernel(
    const unsigned short* __restrict__ ch, const unsigned short* __restrict__ cl,
    const unsigned short* __restrict__ Woh, const unsigned short* __restrict__ Wol,
    const float* __restrict__ bo, float* __restrict__ out)
{
    __shared__ unsigned short sAh[4096], sAl[4096], sBh[4096], sBl[4096];
    const int tid = threadIdx.x, lane = tid & 63, wid = tid >> 6;
    const int wr = wid >> 1, wc = wid & 1;
    const int fTile = blockIdx.x >> 5;   // 0..3
    const int tTile = blockIdx.x & 31;   // 0..31

    f32x4 acc[4][4];
    mfma_core_128(ch, cl, tTile * 128, Woh, Wol, fTile * 128,
                  sAh, sAl, sBh, sBl, acc, wid, lane, wr, wc);
    #pragma unroll
    for (int i = 0; i < 4; ++i) {
        int tBase = tTile * 128 + wr * 64 + i * 16 + (lane >> 4) * 4;
        #pragma unroll
        for (int j = 0; j < 4; ++j) {
            int f = fTile * 128 + wc * 64 + j * 16 + (lane & 15);
            float bof = bo[f];
            #pragma unroll
            for (int r = 0; r < 4; ++r)
                out[(size_t)(tBase + r) * 512 + f] = acc[i][j][r] + bof;
        }
    }
}

// ---------------------------------------------------------------------------
extern "C" void kernel_launch(void* const* d_in, const int* in_sizes, int n_in,
                              void* d_out, int out_size, void* d_ws, size_t ws_size,
                              hipStream_t stream)
{
    (void)in_sizes; (void)n_in; (void)out_size; (void)ws_size;
    const float* x   = (const float*)d_in[0];
    const float* rel = (const float*)d_in[1];
    const float* Wq  = (const float*)d_in[2];
    const float* bq  = (const float*)d_in[3];
    const float* Wk  = (const float*)d_in[4];
    const float* bk  = (const float*)d_in[5];
    const float* Wv  = (const float*)d_in[6];
    const float* bv  = (const float*)d_in[7];
    const float* Wo  = (const float*)d_in[8];
    const float* bo  = (const float*)d_in[9];
    float* out = (float*)d_out;

    // workspace layout (~47 MB)
    float* ws = (float*)d_ws;
    float* biasQK = ws;                        // 262144 f32
    float* sin_t  = biasQK + 262144;           // 16384
    float* cos_t  = sin_t + 16384;             // 16384
    float* Qt     = cos_t + 16384;             // 64*64*512 f32  [bh][d][l]
    float* Kt     = Qt + 2097152;
    float* Vw     = Kt + 2097152;              // [bh][l][d]
    unsigned short* xh  = (unsigned short*)(Vw + 2097152);  // 4096*512 bf16
    unsigned short* xl  = xh + 2097152;
    unsigned short* Wqh = xl + 2097152;        // 512*512 each
    unsigned short* Wql = Wqh + 262144;
    unsigned short* Wkh = Wql + 262144;
    unsigned short* Wkl = Wkh + 262144;
    unsigned short* Wvh = Wkl + 262144;
    unsigned short* Wvl = Wvh + 262144;
    unsigned short* Woh = Wvl + 262144;
    unsigned short* Wol = Woh + 262144;
    unsigned short* ctxh = Wol + 262144;       // 4096*512
    unsigned short* ctxl = ctxh + 2097152;

    prep_kernel<<<68672, 256, 0, stream>>>(rel, x, Wq, Wk, Wv, Wo,
                                           biasQK, sin_t, cos_t,
                                           xh, xl, Wqh, Wql, Wkh, Wkl,
                                           Wvh, Wvl, Woh, Wol);
    qkv_mfma_kernel<<<dim3(128, 3), 256, 0, stream>>>(xh, xl, Wqh, Wql, Wkh, Wkl,
                                                      Wvh, Wvl, bq, bk, bv,
                                                      sin_t, cos_t, Qt, Kt, Vw);
    attn_kernel<<<dim3(8, 64), 256, 0, stream>>>(Qt, Kt, Vw, biasQK, ctxh, ctxl);
    out_mfma_kernel<<<128, 256, 0, stream>>>(ctxh, ctxl, Woh, Wol, bo, out);
}